// Round 5
// baseline (231.202 us; speedup 1.0000x reference)
//
#include <hip/hip_runtime.h>

// Attention block: B=16, C=512, N=1024(=32x32), GROUPS=8, EPS=1e-5
// All GEMMs NT-form bf16 MFMA (A[M][K] x B[N][K]^T), 128x128 tiles.
//
// R5: K-loop restructured for latency hiding. R4 showed MfmaUtil 20% /
// VALU 16% / occ 18% -- latency-bound: glds16+vmcnt(0)+barrier exposes full
// L2 latency every iteration. Now: global_load -> VGPR prefetch of tile k+1
// issued BEFORE MFMAs of tile k, ds_write into double-buffered LDS, ONE
// barrier per iteration. vmcnt wait lands after ~300 cyc of MFMA/ds_read.
//
// Layouts: hn_t[B][N][C], QKt[B][N][1024]=[Q|K], V[B][C][N],
//          expS bf16 [B][N][N], At[B][N][C] (aliases dead hn_t).

#define BATCH 16
#define CCH 512
#define NSP 1024
#define EPSV 1e-5f
#define BK 32    // shorts per K-step
#define BUFSZ 4096  // shorts per LDS tile buffer (128*BK)

typedef short bf16x8 __attribute__((ext_vector_type(8)));
typedef float f32x4 __attribute__((ext_vector_type(4)));

__device__ __forceinline__ unsigned short f2bf(float f) {
    unsigned int u = __float_as_uint(f);
    u += 0x7FFF + ((u >> 16) & 1);  // RNE
    return (unsigned short)(u >> 16);
}

// Decode 1-D block id -> (x, y, b) with batch pinned to XCD (lin%8).
#define XCD_MAP(GX_LOG2, PER, xv, yv, bv)                 \
    const int lin_ = blockIdx.x;                          \
    const int xcd_ = lin_ & 7;                            \
    int slot_ = lin_ >> 3;                                \
    const int hi_ = (slot_ >= (PER)) ? 1 : 0;             \
    const int bv = xcd_ + 8 * hi_;                        \
    slot_ -= hi_ * (PER);                                 \
    const int xv = slot_ & ((1 << (GX_LOG2)) - 1);        \
    const int yv = slot_ >> (GX_LOG2);

// ---------------- shared 128x128 NT mainloop, dbuf + reg prefetch ---------
// Al/Bl each 2*BUFSZ shorts (two buffers).
__device__ __forceinline__ void gemm128_loop(
    const unsigned short* __restrict__ Ag, const unsigned short* __restrict__ Bg,
    int astr, int bstr, int ktot, short* Al, short* Bl, f32x4* acc) {
    const int t = threadIdx.x;
    const int w = t >> 6, lane = t & 63;
    const int wr = (w >> 1) * 64, wc = (w & 1) * 64;
    const int fr = lane & 15, fko = (lane >> 4) * 8;
    const int r0 = t >> 2;        // staging row (4 chunks/row)
    const int kc = (t & 3) * 8;   // staging k-offset (shorts)
    const unsigned short* Ap0 = Ag + (size_t)r0 * astr + kc;
    const unsigned short* Ap1 = Ag + (size_t)(r0 + 64) * astr + kc;
    const unsigned short* Bp0 = Bg + (size_t)r0 * bstr + kc;
    const unsigned short* Bp1 = Bg + (size_t)(r0 + 64) * bstr + kc;
    const int wof0 = r0 * BK + kc;
    const int wof1 = (r0 + 64) * BK + kc;
    // prologue: stage k=0 into buf0
    bf16x8 ra0 = *(const bf16x8*)Ap0;
    bf16x8 ra1 = *(const bf16x8*)Ap1;
    bf16x8 rb0 = *(const bf16x8*)Bp0;
    bf16x8 rb1 = *(const bf16x8*)Bp1;
    *(bf16x8*)(Al + wof0) = ra0;
    *(bf16x8*)(Al + wof1) = ra1;
    *(bf16x8*)(Bl + wof0) = rb0;
    *(bf16x8*)(Bl + wof1) = rb1;
    __syncthreads();
    const int nk = ktot / BK;
    int buf = 0;
    for (int k = 0; k < nk - 1; k++) {
        // issue next tile's global loads first (vmcnt pending through MFMAs)
        const int kof = (k + 1) * BK;
        ra0 = *(const bf16x8*)(Ap0 + kof);
        ra1 = *(const bf16x8*)(Ap1 + kof);
        rb0 = *(const bf16x8*)(Bp0 + kof);
        rb1 = *(const bf16x8*)(Bp1 + kof);
        const short* Ab = Al + buf * BUFSZ;
        const short* Bb = Bl + buf * BUFSZ;
        bf16x8 af[4], bfr[4];
#pragma unroll
        for (int mi = 0; mi < 4; mi++)
            af[mi] = *(const bf16x8*)(Ab + (wr + mi * 16 + fr) * BK + fko);
#pragma unroll
        for (int ni = 0; ni < 4; ni++)
            bfr[ni] = *(const bf16x8*)(Bb + (wc + ni * 16 + fr) * BK + fko);
#pragma unroll
        for (int mi = 0; mi < 4; mi++)
#pragma unroll
            for (int ni = 0; ni < 4; ni++)
                acc[mi * 4 + ni] = __builtin_amdgcn_mfma_f32_16x16x32_bf16(
                    af[mi], bfr[ni], acc[mi * 4 + ni], 0, 0, 0);
        buf ^= 1;
        // waitcnt for ra/rb lands here, after the MFMA block
        *(bf16x8*)(Al + buf * BUFSZ + wof0) = ra0;
        *(bf16x8*)(Al + buf * BUFSZ + wof1) = ra1;
        *(bf16x8*)(Bl + buf * BUFSZ + wof0) = rb0;
        *(bf16x8*)(Bl + buf * BUFSZ + wof1) = rb1;
        __syncthreads();  // one barrier/iter: publishes buf, retires old reads
    }
    // last tile
    const short* Ab = Al + buf * BUFSZ;
    const short* Bb = Bl + buf * BUFSZ;
    bf16x8 af[4], bfr[4];
#pragma unroll
    for (int mi = 0; mi < 4; mi++)
        af[mi] = *(const bf16x8*)(Ab + (wr + mi * 16 + fr) * BK + fko);
#pragma unroll
    for (int ni = 0; ni < 4; ni++)
        bfr[ni] = *(const bf16x8*)(Bb + (wc + ni * 16 + fr) * BK + fko);
#pragma unroll
    for (int mi = 0; mi < 4; mi++)
#pragma unroll
        for (int ni = 0; ni < 4; ni++)
            acc[mi * 4 + ni] = __builtin_amdgcn_mfma_f32_16x16x32_bf16(
                af[mi], bfr[ni], acc[mi * 4 + ni], 0, 0, 0);
}

#define EPI_SETUP()                                          \
    const int t = threadIdx.x, lane = t & 63, w = t >> 6;    \
    const int wr = (w >> 1) * 64, wc = (w & 1) * 64;         \
    const int fr = lane & 15, rr0 = (lane >> 4) * 4;

#define ACC_INIT(acc)                                        \
    f32x4 acc[16];                                           \
    _Pragma("unroll") for (int i = 0; i < 16; i++)           \
        acc[i] = (f32x4){0.f, 0.f, 0.f, 0.f};

// -- setup: GN stats (0..127) + weight cvt (128..1151) + Lsum zero (1152..) --
__global__ __launch_bounds__(256) void setup_k(
    const float* __restrict__ x, float* __restrict__ stats,
    const float* __restrict__ wa, unsigned short* __restrict__ oa, int na4,
    const float* __restrict__ wb, unsigned short* __restrict__ ob, int nb4,
    float* __restrict__ Lsum) {
    const int t = threadIdx.x;
    if (blockIdx.x < 128) {
        const int bg = blockIdx.x;
        const float4* xp = (const float4*)(x + (size_t)bg * 65536);
        float s = 0.f, q = 0.f;
#pragma unroll
        for (int i = 0; i < 64; i++) {
            float4 v = xp[t + i * 256];
            s += v.x + v.y + v.z + v.w;
            q += v.x * v.x + v.y * v.y + v.z * v.z + v.w * v.w;
        }
#pragma unroll
        for (int off = 32; off; off >>= 1) {
            s += __shfl_down(s, off);
            q += __shfl_down(q, off);
        }
        __shared__ float rs[4], rq[4];
        const int wave = t >> 6, lane = t & 63;
        if (lane == 0) { rs[wave] = s; rq[wave] = q; }
        __syncthreads();
        if (t == 0) {
            float S = rs[0] + rs[1] + rs[2] + rs[3];
            float Q = rq[0] + rq[1] + rq[2] + rq[3];
            const float inv = 1.f / 65536.f;
            float mean = S * inv;
            float var = Q * inv - mean * mean;
            stats[bg * 2] = mean;
            stats[bg * 2 + 1] = rsqrtf(var + EPSV);
        }
    } else if (blockIdx.x < 1152) {
        int i = (blockIdx.x - 128) * 256 + t;
        const float* src;
        unsigned short* dst;
        int j;
        if (i < na4) { src = wa; dst = oa; j = i; }
        else { j = i - na4; if (j >= nb4) return; src = wb; dst = ob; }
        float4 v = ((const float4*)src)[j];
        ushort4 o;
        o.x = f2bf(v.x); o.y = f2bf(v.y); o.z = f2bf(v.z); o.w = f2bf(v.w);
        ((ushort4*)dst)[j] = o;
    } else {
        int i = (blockIdx.x - 1152) * 256 + t;  // 16 blocks x 256 float4
        ((float4*)Lsum)[i] = (float4){0.f, 0.f, 0.f, 0.f};
    }
}

// ---------------- GN normalize + transpose -> hn_t[B][N][C] bf16 --------
__global__ __launch_bounds__(256) void gn_tr_k(
    const float* __restrict__ x, const float* __restrict__ gamma,
    const float* __restrict__ beta, const float* __restrict__ stats,
    unsigned short* __restrict__ hn_t) {
    const int nt = blockIdx.x, ct = blockIdx.y, b = blockIdx.z;
    __shared__ __align__(16) unsigned short T[64 * 72];  // [n][c] +pad
    const int t = threadIdx.x;
    const float mean = stats[(b * 8 + ct) * 2];
    const float rstd = stats[(b * 8 + ct) * 2 + 1];
    const int cl = t >> 2, nc = t & 3;
    const int c = ct * 64 + cl;
    const float ga = gamma[c] * rstd;
    const float be = beta[c] - mean * ga;
    const float4* xp = (const float4*)(x + ((size_t)b * CCH + c) * NSP + nt * 64);
#pragma unroll
    for (int j = 0; j < 4; j++) {
        float4 v = xp[nc * 4 + j];
        int n = nc * 16 + j * 4;
        T[(n + 0) * 72 + cl] = f2bf(v.x * ga + be);
        T[(n + 1) * 72 + cl] = f2bf(v.y * ga + be);
        T[(n + 2) * 72 + cl] = f2bf(v.z * ga + be);
        T[(n + 3) * 72 + cl] = f2bf(v.w * ga + be);
    }
    __syncthreads();
    const int nl = t >> 2, cc = t & 3;
    unsigned short* dst = hn_t + ((size_t)b * NSP + nt * 64 + nl) * CCH + ct * 64 + cc * 16;
    const unsigned short* src = T + nl * 72 + cc * 16;
    *(uint4*)dst = *(const uint4*)src;
    *(uint4*)(dst + 8) = *(const uint4*)(src + 8);
}

// ---------------- QKV (merged): y<8 -> Q|K rows, y>=8 -> V (transposed) ----
// grid: 1536 blocks, GX=8 (ntc), GY=12 (y), PER=96
__global__ __launch_bounds__(256) void gemm_qkv_k(
    const unsigned short* __restrict__ hn_t, const unsigned short* __restrict__ wq,
    const float* __restrict__ bq, unsigned short* __restrict__ QKt,
    unsigned short* __restrict__ Vb) {
    __shared__ __align__(16) short Al[2 * BUFSZ], Bl[2 * BUFSZ];
    XCD_MAP(3, 96, xb, y, b);
    const int ntc = xb * 128;
    ACC_INIT(acc);
    if (y < 8) {
        const int mt = y * 128;
        gemm128_loop(hn_t + ((size_t)b * NSP + mt) * CCH,
                     wq + (size_t)ntc * CCH, CCH, CCH, CCH, Al, Bl, acc);
        unsigned short* Ob = QKt + (size_t)b * NSP * 1024;
        EPI_SETUP();
#pragma unroll
        for (int ni = 0; ni < 4; ni++) {
            int col = ntc + wc + ni * 16 + fr;
            float bias = bq[col];
#pragma unroll
            for (int mi = 0; mi < 4; mi++) {
                int row = mt + wr + mi * 16 + rr0;
#pragma unroll
                for (int r = 0; r < 4; r++)
                    Ob[(size_t)(row + r) * 1024 + col] = f2bf(acc[mi * 4 + ni][r] + bias);
            }
        }
    } else {
        const int mt = (y - 8) * 128;
        gemm128_loop(wq + (size_t)(1024 + mt) * CCH,
                     hn_t + ((size_t)b * NSP + ntc) * CCH, CCH, CCH, CCH, Al, Bl, acc);
        unsigned short* Ob = Vb + (size_t)b * CCH * NSP;
        EPI_SETUP();
#pragma unroll
        for (int mi = 0; mi < 4; mi++) {
            int row = mt + wr + mi * 16 + rr0;
#pragma unroll
            for (int r = 0; r < 4; r++) {
                float bias = bq[1024 + row + r];
#pragma unroll
                for (int ni = 0; ni < 4; ni++) {
                    int col = ntc + wc + ni * 16 + fr;
                    Ob[(size_t)(row + r) * NSP + col] = f2bf(acc[mi * 4 + ni][r] + bias);
                }
            }
        }
    }
}

// ------- scores+exp: expS[b][n][m]=exp(scale*q.k) bf16; Lsum[b][n] += rowsum ----
// grid: 1024 blocks, GX=8 (nt), GY=8 (mt), PER=64
__global__ __launch_bounds__(256) void gemm_scores_k(
    const unsigned short* __restrict__ QKt, unsigned short* __restrict__ expS,
    float* __restrict__ Lsum) {
    __shared__ __align__(16) short Al[2 * BUFSZ], Bl[2 * BUFSZ];
    XCD_MAP(3, 64, xb, yb, b);
    const int nt = xb * 128, mt = yb * 128;
    const unsigned short* base = QKt + (size_t)b * NSP * 1024;
    ACC_INIT(acc);
    gemm128_loop(base + (size_t)mt * 1024, base + (size_t)nt * 1024 + 512,
                 1024, 1024, 512, Al, Bl, acc);
    unsigned short* Ob = expS + (size_t)b * NSP * NSP;
    float* Ls = Lsum + (size_t)b * NSP;
    const float scale = 0.044194173824159216f;  // 512^-0.5
    EPI_SETUP();
#pragma unroll
    for (int mi = 0; mi < 4; mi++) {
#pragma unroll
        for (int r = 0; r < 4; r++) {
            const int row = mt + wr + mi * 16 + rr0 + r;
            float rs = 0.f;
#pragma unroll
            for (int ni = 0; ni < 4; ni++) {
                int col = nt + wc + ni * 16 + fr;
                float e = __expf(acc[mi * 4 + ni][r] * scale);
                Ob[(size_t)row * NSP + col] = f2bf(e);
                rs += e;
            }
            rs += __shfl_xor(rs, 1);
            rs += __shfl_xor(rs, 2);
            rs += __shfl_xor(rs, 4);
            rs += __shfl_xor(rs, 8);
            if (fr == 0) atomicAdd(&Ls[row], rs);
        }
    }
}

// ---------------- PV: At[b][n][c] = (expS[n][:] . V[c][:]) / Lsum[n] --------
// grid: 512 blocks, GX=4 (ntc), GY=8 (mt), PER=32
__global__ __launch_bounds__(256) void gemm_pv_k(
    const unsigned short* __restrict__ expS, const unsigned short* __restrict__ Vb,
    const float* __restrict__ Lsum, unsigned short* __restrict__ At) {
    __shared__ __align__(16) short Al[2 * BUFSZ], Bl[2 * BUFSZ];
    XCD_MAP(2, 32, xb, yb, b);
    const int ntc = xb * 128, mt = yb * 128;
    ACC_INIT(acc);
    gemm128_loop(expS + ((size_t)b * NSP + mt) * NSP,
                 Vb + ((size_t)b * CCH + ntc) * NSP, NSP, NSP, NSP, Al, Bl, acc);
    unsigned short* Ob = At + (size_t)b * NSP * CCH;
    const float* Ls = Lsum + (size_t)b * NSP;
    EPI_SETUP();
#pragma unroll
    for (int mi = 0; mi < 4; mi++) {
        int row = mt + wr + mi * 16 + rr0;
#pragma unroll
        for (int r = 0; r < 4; r++) {
            float inv = __builtin_amdgcn_rcpf(Ls[row + r]);
#pragma unroll
            for (int ni = 0; ni < 4; ni++) {
                int col = ntc + wc + ni * 16 + fr;
                Ob[(size_t)(row + r) * CCH + col] = f2bf(acc[mi * 4 + ni][r] * inv);
            }
        }
    }
}

// ---------------- proj: out = x + bp[o] + Wp[o][:] . At[n][:] ----------------
// grid: 512 blocks, GX=8 (nt), GY=4 (mt), PER=32
__global__ __launch_bounds__(256) void gemm_proj_k(
    const unsigned short* __restrict__ At, const unsigned short* __restrict__ wp,
    const float* __restrict__ bp, const float* __restrict__ x,
    float* __restrict__ out) {
    __shared__ __align__(16) short Al[2 * BUFSZ], Bl[2 * BUFSZ];
    XCD_MAP(3, 32, xb, yb, b);
    const int nt = xb * 128, mt = yb * 128;
    ACC_INIT(acc);
    gemm128_loop(wp + (size_t)mt * CCH, At + ((size_t)b * NSP + nt) * CCH,
                 CCH, CCH, CCH, Al, Bl, acc);
    const size_t bbase = (size_t)b * CCH * NSP;
    EPI_SETUP();
#pragma unroll
    for (int mi = 0; mi < 4; mi++) {
        int row = mt + wr + mi * 16 + rr0;
#pragma unroll
        for (int r = 0; r < 4; r++) {
            float bias = bp[row + r];
#pragma unroll
            for (int ni = 0; ni < 4; ni++) {
                int col = nt + wc + ni * 16 + fr;
                size_t idx = bbase + (size_t)(row + r) * NSP + col;
                out[idx] = x[idx] + bias + acc[mi * 4 + ni][r];
            }
        }
    }
}

extern "C" void kernel_launch(void* const* d_in, const int* in_sizes, int n_in,
                              void* d_out, int out_size, void* d_ws, size_t ws_size,
                              hipStream_t stream) {
    const float* x = (const float*)d_in[0];
    const float* gamma = (const float*)d_in[1];
    const float* beta = (const float*)d_in[2];
    const float* w_qkv = (const float*)d_in[3];
    const float* b_qkv = (const float*)d_in[4];
    const float* w_proj = (const float*)d_in[5];
    const float* b_proj = (const float*)d_in[6];
    float* out = (float*)d_out;

    char* ws = (char*)d_ws;
    const size_t MB = 1048576;
    unsigned short* wqkv_bf = (unsigned short*)ws;               // 1.5 MiB
    unsigned short* wproj_bf = (unsigned short*)(ws + 1572864);  // 0.5 MiB
    float* stats = (float*)(ws + 2 * MB);                        // 1 KiB
    float* Lsum = (float*)(ws + 2 * MB + 65536);                 // 64 KiB
    unsigned short* hn_t = (unsigned short*)(ws + 4 * MB);       // 16.8 MiB
    unsigned short* At = hn_t;                                   // aliases dead hn_t
    unsigned short* QKt = (unsigned short*)(ws + 24 * MB);       // 33.5 MiB
    unsigned short* Vb = (unsigned short*)(ws + 60 * MB);        // 16.8 MiB
    unsigned short* expS = (unsigned short*)(ws + 80 * MB);      // 33.5 MiB

    setup_k<<<1168, 256, 0, stream>>>(x, stats, w_qkv, wqkv_bf, 196608,
                                      w_proj, wproj_bf, 65536, Lsum);
    gn_tr_k<<<dim3(16, 8, BATCH), 256, 0, stream>>>(x, gamma, beta, stats, hn_t);
    gemm_qkv_k<<<1536, 256, 0, stream>>>(hn_t, wqkv_bf, b_qkv, QKt, Vb);
    gemm_scores_k<<<1024, 256, 0, stream>>>(QKt, expS, Lsum);
    gemm_pv_k<<<512, 256, 0, stream>>>(expS, Vb, Lsum, At);
    gemm_proj_k<<<512, 256, 0, stream>>>(At, wproj_bf, b_proj, x, out);
}

// Round 6
// 209.812 us; speedup vs baseline: 1.1019x; 1.1019x over previous
//
#include <hip/hip_runtime.h>

// Attention block: B=16, C=512, N=1024(=32x32), GROUPS=8, EPS=1e-5
// All GEMMs NT-form bf16 MFMA (A[M][K] x B[N][K]^T), 128x128 tiles,
// global_load_lds width-16 staging (m97 pattern).
//
// R6: R5's reg-prefetch dbuf REGRESSED (47->59us) -- reverted to R4's glds16
// loop, but now stage K=64 per barrier pair as two packed [128][32]
// half-tiles (8 glds16 issued together, one sync, 32 MFMAs, one sync).
// Halves barrier-drain count; LDS 32KB; row stride stays 64B (same benign
// bank behavior as R4).
//
// Layouts: hn_t[B][N][C], QKt[B][N][1024]=[Q|K], V[B][C][N],
//          expS bf16 [B][N][N], At[B][N][C] (aliases dead hn_t).

#define BATCH 16
#define CCH 512
#define NSP 1024
#define EPSV 1e-5f
#define BK 32      // shorts per half-tile row
#define HT 4096    // shorts per half-tile (128*BK)

typedef short bf16x8 __attribute__((ext_vector_type(8)));
typedef float f32x4 __attribute__((ext_vector_type(4)));

__device__ __forceinline__ unsigned short f2bf(float f) {
    unsigned int u = __float_as_uint(f);
    u += 0x7FFF + ((u >> 16) & 1);  // RNE
    return (unsigned short)(u >> 16);
}

__device__ __forceinline__ void glds16(const void* g, void* l) {
    __builtin_amdgcn_global_load_lds(
        (const __attribute__((address_space(1))) unsigned int*)g,
        (__attribute__((address_space(3))) unsigned int*)l, 16, 0, 0);
}

// Decode 1-D block id -> (x, y, b) with batch pinned to XCD (lin%8).
#define XCD_MAP(GX_LOG2, PER, xv, yv, bv)                 \
    const int lin_ = blockIdx.x;                          \
    const int xcd_ = lin_ & 7;                            \
    int slot_ = lin_ >> 3;                                \
    const int hi_ = (slot_ >= (PER)) ? 1 : 0;             \
    const int bv = xcd_ + 8 * hi_;                        \
    slot_ -= hi_ * (PER);                                 \
    const int xv = slot_ & ((1 << (GX_LOG2)) - 1);        \
    const int yv = slot_ >> (GX_LOG2);

// ---------------- shared 128x128 NT mainloop, K=64 per barrier pair -------
// Al/Bl each 2*HT shorts (two K-half tiles, each [128][BK] packed).
__device__ __forceinline__ void gemm128_loop(
    const unsigned short* __restrict__ Ag, const unsigned short* __restrict__ Bg,
    int astr, int bstr, int ktot, short* Al, short* Bl, f32x4* acc) {
    const int t = threadIdx.x;
    const int w = t >> 6, lane = t & 63;
    const int wr = (w >> 1) * 64, wc = (w & 1) * 64;
    const int fr = lane & 15, fko = (lane >> 4) * 8;
    const int r0 = t >> 2;        // staging row (4 chunks/row)
    const int kc = (t & 3) * 8;   // staging k-offset (shorts)
    const unsigned short* Ap0 = Ag + (size_t)r0 * astr + kc;
    const unsigned short* Ap1 = Ag + (size_t)(r0 + 64) * astr + kc;
    const unsigned short* Bp0 = Bg + (size_t)r0 * bstr + kc;
    const unsigned short* Bp1 = Bg + (size_t)(r0 + 64) * bstr + kc;
    short* Alw = Al + w * 512;   // wave-uniform LDS base (lane*16B contiguous)
    short* Blw = Bl + w * 512;
    for (int k0 = 0; k0 < ktot; k0 += 64) {
        glds16(Ap0 + k0, Alw);
        glds16(Ap1 + k0, Alw + 2048);
        glds16(Ap0 + k0 + 32, Alw + HT);
        glds16(Ap1 + k0 + 32, Alw + HT + 2048);
        glds16(Bp0 + k0, Blw);
        glds16(Bp1 + k0, Blw + 2048);
        glds16(Bp0 + k0 + 32, Blw + HT);
        glds16(Bp1 + k0 + 32, Blw + HT + 2048);
        __syncthreads();
#pragma unroll
        for (int h = 0; h < 2; h++) {
            const short* Ab = Al + h * HT;
            const short* Bb = Bl + h * HT;
            bf16x8 af[4], bfr[4];
#pragma unroll
            for (int mi = 0; mi < 4; mi++)
                af[mi] = *(const bf16x8*)(Ab + (wr + mi * 16 + fr) * BK + fko);
#pragma unroll
            for (int ni = 0; ni < 4; ni++)
                bfr[ni] = *(const bf16x8*)(Bb + (wc + ni * 16 + fr) * BK + fko);
#pragma unroll
            for (int mi = 0; mi < 4; mi++)
#pragma unroll
                for (int ni = 0; ni < 4; ni++)
                    acc[mi * 4 + ni] = __builtin_amdgcn_mfma_f32_16x16x32_bf16(
                        af[mi], bfr[ni], acc[mi * 4 + ni], 0, 0, 0);
        }
        __syncthreads();
    }
}

#define EPI_SETUP()                                          \
    const int t = threadIdx.x, lane = t & 63, w = t >> 6;    \
    const int wr = (w >> 1) * 64, wc = (w & 1) * 64;         \
    const int fr = lane & 15, rr0 = (lane >> 4) * 4;

#define ACC_INIT(acc)                                        \
    f32x4 acc[16];                                           \
    _Pragma("unroll") for (int i = 0; i < 16; i++)           \
        acc[i] = (f32x4){0.f, 0.f, 0.f, 0.f};

// -- setup: GN stats (0..127) + weight cvt (128..1151) + Lsum zero (1152..) --
__global__ __launch_bounds__(256) void setup_k(
    const float* __restrict__ x, float* __restrict__ stats,
    const float* __restrict__ wa, unsigned short* __restrict__ oa, int na4,
    const float* __restrict__ wb, unsigned short* __restrict__ ob, int nb4,
    float* __restrict__ Lsum) {
    const int t = threadIdx.x;
    if (blockIdx.x < 128) {
        const int bg = blockIdx.x;
        const float4* xp = (const float4*)(x + (size_t)bg * 65536);
        float s = 0.f, q = 0.f;
#pragma unroll
        for (int i = 0; i < 64; i++) {
            float4 v = xp[t + i * 256];
            s += v.x + v.y + v.z + v.w;
            q += v.x * v.x + v.y * v.y + v.z * v.z + v.w * v.w;
        }
#pragma unroll
        for (int off = 32; off; off >>= 1) {
            s += __shfl_down(s, off);
            q += __shfl_down(q, off);
        }
        __shared__ float rs[4], rq[4];
        const int wave = t >> 6, lane = t & 63;
        if (lane == 0) { rs[wave] = s; rq[wave] = q; }
        __syncthreads();
        if (t == 0) {
            float S = rs[0] + rs[1] + rs[2] + rs[3];
            float Q = rq[0] + rq[1] + rq[2] + rq[3];
            const float inv = 1.f / 65536.f;
            float mean = S * inv;
            float var = Q * inv - mean * mean;
            stats[bg * 2] = mean;
            stats[bg * 2 + 1] = rsqrtf(var + EPSV);
        }
    } else if (blockIdx.x < 1152) {
        int i = (blockIdx.x - 128) * 256 + t;
        const float* src;
        unsigned short* dst;
        int j;
        if (i < na4) { src = wa; dst = oa; j = i; }
        else { j = i - na4; if (j >= nb4) return; src = wb; dst = ob; }
        float4 v = ((const float4*)src)[j];
        ushort4 o;
        o.x = f2bf(v.x); o.y = f2bf(v.y); o.z = f2bf(v.z); o.w = f2bf(v.w);
        ((ushort4*)dst)[j] = o;
    } else {
        int i = (blockIdx.x - 1152) * 256 + t;  // 16 blocks x 256 float4
        ((float4*)Lsum)[i] = (float4){0.f, 0.f, 0.f, 0.f};
    }
}

// ---------------- GN normalize + transpose -> hn_t[B][N][C] bf16 --------
__global__ __launch_bounds__(256) void gn_tr_k(
    const float* __restrict__ x, const float* __restrict__ gamma,
    const float* __restrict__ beta, const float* __restrict__ stats,
    unsigned short* __restrict__ hn_t) {
    const int nt = blockIdx.x, ct = blockIdx.y, b = blockIdx.z;
    __shared__ __align__(16) unsigned short T[64 * 72];  // [n][c] +pad
    const int t = threadIdx.x;
    const float mean = stats[(b * 8 + ct) * 2];
    const float rstd = stats[(b * 8 + ct) * 2 + 1];
    const int cl = t >> 2, nc = t & 3;
    const int c = ct * 64 + cl;
    const float ga = gamma[c] * rstd;
    const float be = beta[c] - mean * ga;
    const float4* xp = (const float4*)(x + ((size_t)b * CCH + c) * NSP + nt * 64);
#pragma unroll
    for (int j = 0; j < 4; j++) {
        float4 v = xp[nc * 4 + j];
        int n = nc * 16 + j * 4;
        T[(n + 0) * 72 + cl] = f2bf(v.x * ga + be);
        T[(n + 1) * 72 + cl] = f2bf(v.y * ga + be);
        T[(n + 2) * 72 + cl] = f2bf(v.z * ga + be);
        T[(n + 3) * 72 + cl] = f2bf(v.w * ga + be);
    }
    __syncthreads();
    const int nl = t >> 2, cc = t & 3;
    unsigned short* dst = hn_t + ((size_t)b * NSP + nt * 64 + nl) * CCH + ct * 64 + cc * 16;
    const unsigned short* src = T + nl * 72 + cc * 16;
    *(uint4*)dst = *(const uint4*)src;
    *(uint4*)(dst + 8) = *(const uint4*)(src + 8);
}

// ---------------- QKV (merged): y<8 -> Q|K rows, y>=8 -> V (transposed) ----
// grid: 1536 blocks, GX=8 (ntc), GY=12 (y), PER=96
__global__ __launch_bounds__(256) void gemm_qkv_k(
    const unsigned short* __restrict__ hn_t, const unsigned short* __restrict__ wq,
    const float* __restrict__ bq, unsigned short* __restrict__ QKt,
    unsigned short* __restrict__ Vb) {
    __shared__ __align__(16) short Al[2 * HT], Bl[2 * HT];
    XCD_MAP(3, 96, xb, y, b);
    const int ntc = xb * 128;
    ACC_INIT(acc);
    if (y < 8) {
        const int mt = y * 128;
        gemm128_loop(hn_t + ((size_t)b * NSP + mt) * CCH,
                     wq + (size_t)ntc * CCH, CCH, CCH, CCH, Al, Bl, acc);
        unsigned short* Ob = QKt + (size_t)b * NSP * 1024;
        EPI_SETUP();
#pragma unroll
        for (int ni = 0; ni < 4; ni++) {
            int col = ntc + wc + ni * 16 + fr;
            float bias = bq[col];
#pragma unroll
            for (int mi = 0; mi < 4; mi++) {
                int row = mt + wr + mi * 16 + rr0;
#pragma unroll
                for (int r = 0; r < 4; r++)
                    Ob[(size_t)(row + r) * 1024 + col] = f2bf(acc[mi * 4 + ni][r] + bias);
            }
        }
    } else {
        const int mt = (y - 8) * 128;
        gemm128_loop(wq + (size_t)(1024 + mt) * CCH,
                     hn_t + ((size_t)b * NSP + ntc) * CCH, CCH, CCH, CCH, Al, Bl, acc);
        unsigned short* Ob = Vb + (size_t)b * CCH * NSP;
        EPI_SETUP();
#pragma unroll
        for (int mi = 0; mi < 4; mi++) {
            int row = mt + wr + mi * 16 + rr0;
#pragma unroll
            for (int r = 0; r < 4; r++) {
                float bias = bq[1024 + row + r];
#pragma unroll
                for (int ni = 0; ni < 4; ni++) {
                    int col = ntc + wc + ni * 16 + fr;
                    Ob[(size_t)(row + r) * NSP + col] = f2bf(acc[mi * 4 + ni][r] + bias);
                }
            }
        }
    }
}

// ------- scores+exp: expS[b][n][m]=exp(scale*q.k) bf16; Lsum[b][n] += rowsum ----
// grid: 1024 blocks, GX=8 (nt), GY=8 (mt), PER=64
__global__ __launch_bounds__(256) void gemm_scores_k(
    const unsigned short* __restrict__ QKt, unsigned short* __restrict__ expS,
    float* __restrict__ Lsum) {
    __shared__ __align__(16) short Al[2 * HT], Bl[2 * HT];
    XCD_MAP(3, 64, xb, yb, b);
    const int nt = xb * 128, mt = yb * 128;
    const unsigned short* base = QKt + (size_t)b * NSP * 1024;
    ACC_INIT(acc);
    gemm128_loop(base + (size_t)mt * 1024, base + (size_t)nt * 1024 + 512,
                 1024, 1024, 512, Al, Bl, acc);
    unsigned short* Ob = expS + (size_t)b * NSP * NSP;
    float* Ls = Lsum + (size_t)b * NSP;
    const float scale = 0.044194173824159216f;  // 512^-0.5
    EPI_SETUP();
#pragma unroll
    for (int mi = 0; mi < 4; mi++) {
#pragma unroll
        for (int r = 0; r < 4; r++) {
            const int row = mt + wr + mi * 16 + rr0 + r;
            float rs = 0.f;
#pragma unroll
            for (int ni = 0; ni < 4; ni++) {
                int col = nt + wc + ni * 16 + fr;
                float e = __expf(acc[mi * 4 + ni][r] * scale);
                Ob[(size_t)row * NSP + col] = f2bf(e);
                rs += e;
            }
            rs += __shfl_xor(rs, 1);
            rs += __shfl_xor(rs, 2);
            rs += __shfl_xor(rs, 4);
            rs += __shfl_xor(rs, 8);
            if (fr == 0) atomicAdd(&Ls[row], rs);
        }
    }
}

// ---------------- PV: At[b][n][c] = (expS[n][:] . V[c][:]) / Lsum[n] --------
// grid: 512 blocks, GX=4 (ntc), GY=8 (mt), PER=32
__global__ __launch_bounds__(256) void gemm_pv_k(
    const unsigned short* __restrict__ expS, const unsigned short* __restrict__ Vb,
    const float* __restrict__ Lsum, unsigned short* __restrict__ At) {
    __shared__ __align__(16) short Al[2 * HT], Bl[2 * HT];
    XCD_MAP(2, 32, xb, yb, b);
    const int ntc = xb * 128, mt = yb * 128;
    ACC_INIT(acc);
    gemm128_loop(expS + ((size_t)b * NSP + mt) * NSP,
                 Vb + ((size_t)b * CCH + ntc) * NSP, NSP, NSP, NSP, Al, Bl, acc);
    unsigned short* Ob = At + (size_t)b * NSP * CCH;
    const float* Ls = Lsum + (size_t)b * NSP;
    EPI_SETUP();
#pragma unroll
    for (int mi = 0; mi < 4; mi++) {
        int row = mt + wr + mi * 16 + rr0;
#pragma unroll
        for (int r = 0; r < 4; r++) {
            float inv = __builtin_amdgcn_rcpf(Ls[row + r]);
#pragma unroll
            for (int ni = 0; ni < 4; ni++) {
                int col = ntc + wc + ni * 16 + fr;
                Ob[(size_t)(row + r) * CCH + col] = f2bf(acc[mi * 4 + ni][r] * inv);
            }
        }
    }
}

// ---------------- proj: out = x + bp[o] + Wp[o][:] . At[n][:] ----------------
// grid: 512 blocks, GX=8 (nt), GY=4 (mt), PER=32
__global__ __launch_bounds__(256) void gemm_proj_k(
    const unsigned short* __restrict__ At, const unsigned short* __restrict__ wp,
    const float* __restrict__ bp, const float* __restrict__ x,
    float* __restrict__ out) {
    __shared__ __align__(16) short Al[2 * HT], Bl[2 * HT];
    XCD_MAP(3, 32, xb, yb, b);
    const int nt = xb * 128, mt = yb * 128;
    ACC_INIT(acc);
    gemm128_loop(wp + (size_t)mt * CCH, At + ((size_t)b * NSP + nt) * CCH,
                 CCH, CCH, CCH, Al, Bl, acc);
    const size_t bbase = (size_t)b * CCH * NSP;
    EPI_SETUP();
#pragma unroll
    for (int mi = 0; mi < 4; mi++) {
        int row = mt + wr + mi * 16 + rr0;
#pragma unroll
        for (int r = 0; r < 4; r++) {
            float bias = bp[row + r];
#pragma unroll
            for (int ni = 0; ni < 4; ni++) {
                int col = nt + wc + ni * 16 + fr;
                size_t idx = bbase + (size_t)(row + r) * NSP + col;
                out[idx] = x[idx] + bias + acc[mi * 4 + ni][r];
            }
        }
    }
}

extern "C" void kernel_launch(void* const* d_in, const int* in_sizes, int n_in,
                              void* d_out, int out_size, void* d_ws, size_t ws_size,
                              hipStream_t stream) {
    const float* x = (const float*)d_in[0];
    const float* gamma = (const float*)d_in[1];
    const float* beta = (const float*)d_in[2];
    const float* w_qkv = (const float*)d_in[3];
    const float* b_qkv = (const float*)d_in[4];
    const float* w_proj = (const float*)d_in[5];
    const float* b_proj = (const float*)d_in[6];
    float* out = (float*)d_out;

    char* ws = (char*)d_ws;
    const size_t MB = 1048576;
    unsigned short* wqkv_bf = (unsigned short*)ws;               // 1.5 MiB
    unsigned short* wproj_bf = (unsigned short*)(ws + 1572864);  // 0.5 MiB
    float* stats = (float*)(ws + 2 * MB);                        // 1 KiB
    float* Lsum = (float*)(ws + 2 * MB + 65536);                 // 64 KiB
    unsigned short* hn_t = (unsigned short*)(ws + 4 * MB);       // 16.8 MiB
    unsigned short* At = hn_t;                                   // aliases dead hn_t
    unsigned short* QKt = (unsigned short*)(ws + 24 * MB);       // 33.5 MiB
    unsigned short* Vb = (unsigned short*)(ws + 60 * MB);        // 16.8 MiB
    unsigned short* expS = (unsigned short*)(ws + 80 * MB);      // 33.5 MiB

    setup_k<<<1168, 256, 0, stream>>>(x, stats, w_qkv, wqkv_bf, 196608,
                                      w_proj, wproj_bf, 65536, Lsum);
    gn_tr_k<<<dim3(16, 8, BATCH), 256, 0, stream>>>(x, gamma, beta, stats, hn_t);
    gemm_qkv_k<<<1536, 256, 0, stream>>>(hn_t, wqkv_bf, b_qkv, QKt, Vb);
    gemm_scores_k<<<1024, 256, 0, stream>>>(QKt, expS, Lsum);
    gemm_pv_k<<<512, 256, 0, stream>>>(expS, Vb, Lsum, At);
    gemm_proj_k<<<512, 256, 0, stream>>>(At, wproj_bf, b_proj, x, out);
}